// Round 3
// baseline (198.510 us; speedup 1.0000x reference)
//
#include <hip/hip_runtime.h>

// Nearest-neighbor 2x upsample, fp32.
// Input:  [B=16, C=128, H=128, W=128] -> Output: [16, 128, 256, 256]
//
// R3: same as R2 but with clang native vector type (ext_vector_type(4))
// so __builtin_nontemporal_load/store accept the pointer.
// Each thread: load f32x4 {a,b,c,d} -> write {a,a,b,b} {c,c,d,d} to out
// rows 2h and 2h+1. Traffic = 1x read + 4x write, no over-fetch.

#define H_IN   128
#define W_IN   128
#define H_OUT  256
#define W_OUT  256
#define WQUADS (W_IN / 4)   // 32 quads per input row

typedef float f32x4 __attribute__((ext_vector_type(4)));

__global__ __launch_bounds__(256) void nn_upsample2x_kernel(
    const float* __restrict__ in, float* __restrict__ out, int total_quads) {
    int stride = gridDim.x * blockDim.x;
    for (int t = blockIdx.x * blockDim.x + threadIdx.x; t < total_quads; t += stride) {
        int jq  = t & (WQUADS - 1);      // quad index within row: 0..31
        int row = t >> 5;                // global input row: b*C*H + c*H + h
        int h   = row & (H_IN - 1);
        int bc  = row >> 7;              // b*C + c

        const f32x4 v = __builtin_nontemporal_load(
            reinterpret_cast<const f32x4*>(in + (size_t)row * W_IN + jq * 4));

        f32x4 w0 = {v.x, v.x, v.y, v.y};
        f32x4 w1 = {v.z, v.z, v.w, v.w};

        float* o0 = out + ((size_t)bc * H_OUT + 2 * h) * W_OUT + jq * 8;
        __builtin_nontemporal_store(w0, reinterpret_cast<f32x4*>(o0));
        __builtin_nontemporal_store(w1, reinterpret_cast<f32x4*>(o0 + 4));
        __builtin_nontemporal_store(w0, reinterpret_cast<f32x4*>(o0 + W_OUT));
        __builtin_nontemporal_store(w1, reinterpret_cast<f32x4*>(o0 + W_OUT + 4));
    }
}

extern "C" void kernel_launch(void* const* d_in, const int* in_sizes, int n_in,
                              void* d_out, int out_size, void* d_ws, size_t ws_size,
                              hipStream_t stream) {
    const float* in  = (const float*)d_in[0];
    float*       out = (float*)d_out;

    // total input quads = B*C*H * (W/4) = 16*128*128*32 = 8,388,608
    int total_quads = in_sizes[0] / 4;

    const int block = 256;
    const int grid  = 8192;  // grid-stride: 4 iterations/thread
    nn_upsample2x_kernel<<<grid, block, 0, stream>>>(in, out, total_quads);
}

// Round 4
// 102.031 us; speedup vs baseline: 1.9456x; 1.9456x over previous
//
#include <hip/hip_runtime.h>

// Nearest-neighbor 2x upsample, fp32.
// Input:  [B=16, C=128, H=128, W=128] -> Output: [16, 128, 256, 256]
//
// R4: R1 geometry (the 133us version) + nontemporal STORES only.
// Each thread: load float2 {x,y} at (row, jq*2)
//   -> store float4 {x,x,y,y} to out rows 2h and 2h+1 at col jq*4.
// Per store instruction, lane i writes bytes [16i, 16i+16) of ONE output
// row (WPAIRS=64 == wave size, so a wave covers exactly one input row) —
// fully contiguous 1KiB per store instruction. This is the property R3
// broke; nt is safe only with full-line coverage per instruction.

#define H_IN   128
#define W_IN   128
#define H_OUT  256
#define W_OUT  256
#define WPAIRS (W_IN / 2)   // 64 pairs per input row == one wave per row

typedef float f32x4 __attribute__((ext_vector_type(4)));

__global__ __launch_bounds__(256) void nn_upsample2x_kernel(
    const float* __restrict__ in, float* __restrict__ out, int total_pairs) {
    int stride = gridDim.x * blockDim.x;
    for (int t = blockIdx.x * blockDim.x + threadIdx.x; t < total_pairs; t += stride) {
        int jq  = t & (WPAIRS - 1);      // pair index within row: 0..63
        int row = t >> 6;                // global input row: b*C*H + c*H + h
        int h   = row & (H_IN - 1);
        int bc  = row >> 7;              // b*C + c

        const float2 v = *reinterpret_cast<const float2*>(in + (size_t)row * W_IN + jq * 2);
        f32x4 w = {v.x, v.x, v.y, v.y};

        float* o0 = out + ((size_t)bc * H_OUT + 2 * h) * W_OUT + jq * 4;
        __builtin_nontemporal_store(w, reinterpret_cast<f32x4*>(o0));          // row 2h
        __builtin_nontemporal_store(w, reinterpret_cast<f32x4*>(o0 + W_OUT));  // row 2h+1
    }
}

extern "C" void kernel_launch(void* const* d_in, const int* in_sizes, int n_in,
                              void* d_out, int out_size, void* d_ws, size_t ws_size,
                              hipStream_t stream) {
    const float* in  = (const float*)d_in[0];
    float*       out = (float*)d_out;

    // total input pairs = B*C*H * (W/2) = 16*128*128*64 = 16,777,216
    int total_pairs = in_sizes[0] / 2;

    const int block = 256;
    const int grid  = 8192;  // grid-stride: ~8 iterations/thread
    nn_upsample2x_kernel<<<grid, block, 0, stream>>>(in, out, total_pairs);
}